// Round 9
// baseline (360.096 us; speedup 1.0000x reference)
//
#include <hip/hip_runtime.h>
#include <hip/hip_bf16.h>

#define TT 512
#define BB 4096

typedef __attribute__((ext_vector_type(4))) float f32x4;
typedef __attribute__((ext_vector_type(8))) short short8;
typedef __attribute__((ext_vector_type(8))) __bf16 bf16v8;

__device__ __forceinline__ f32x4 MFMA(short8 a, short8 b, f32x4 c) {
    return __builtin_amdgcn_mfma_f32_16x16x32_bf16(
        __builtin_bit_cast(bf16v8, a), __builtin_bit_cast(bf16v8, b), c, 0, 0, 0);
}

__device__ __forceinline__ float fast_rcp(float x) { return __builtin_amdgcn_rcpf(x); }

__device__ __forceinline__ ushort bfbits(float f) {
    return __bfloat16_as_ushort(__float2bfloat16(f));
}
__device__ __forceinline__ float bf2f(ushort u) {
    return __uint_as_float(((unsigned)u) << 16);
}

// B-fragment: pair-duplicated bf16 of 4 f32 values. Against A's interleaved
// (Whi,Wlo) this computes (Whi+Wlo)*bf16(v): W exact to ~17 bits, v in bf16.
__device__ __forceinline__ short8 mk_b(const f32x4& v) {
    short8 B;
#pragma unroll
    for (int q = 0; q < 4; ++q) {
        const short hi = (short)bfbits(v[q]);
        B[2 * q] = hi; B[2 * q + 1] = hi;
    }
    return B;
}

// Gate pre-activation scaling folded into weights/biases:
//   r,z rows scaled by -log2(e)   -> gate = rcp(1 + exp2(acc))
//   n rows scaled by -2*log2(e)   -> tanh = 2*rcp(1 + exp2(acc)) - 1
#define KS1 (-1.44269504088896340736f)
#define KS2 (-2.88539008177792681472f)

// Layer-pipelined GRU, TWO independent pipelines per block (2 waves/SIMD):
//   pipeline p in {0,1}: waves 0..2 = layers (wave L does t=4(s-L)..+3 at superstep s),
//   wave 3 = projection+stores (lag 3). Block = 512 thr = 8 waves; each SIMD hosts
//   the same-role wave of both pipelines -> one wave's trans-latency bubbles are
//   filled by the other's issue. Grid = BB/32 = 128 blocks.
__global__ __launch_bounds__(512, 1)
void gru_pipe4x2_kernel(const float* __restrict__ x, const float* __restrict__ h0,
                        const float* __restrict__ W_emb, const float* __restrict__ b_emb,
                        const float* __restrict__ W_out, const float* __restrict__ b_out,
                        const float* __restrict__ Wih0, const float* __restrict__ Whh0,
                        const float* __restrict__ bih0, const float* __restrict__ bhh0,
                        const float* __restrict__ Wih1, const float* __restrict__ Whh1,
                        const float* __restrict__ bih1, const float* __restrict__ bhh1,
                        const float* __restrict__ Wih2, const float* __restrict__ Whh2,
                        const float* __restrict__ bih2, const float* __restrict__ bhh2,
                        float* __restrict__ out)
{
    const int tid = threadIdx.x;
    const int p   = tid >> 8;          // pipeline 0/1
    const int wid = (tid >> 6) & 3;    // 0..2 layer waves, 3 = projection wave
    const int l   = tid & 63;
    const int n   = l & 15;
    const int g   = l >> 4;
    const int b   = blockIdx.x * 32 + p * 16 + n;

    __shared__ short8 lbuf[2][2][2][4][64];  // 32 KiB [pipe][parity][producer][tslot][lane]
    __shared__ f32x4  obuf[2][2][4][64];     // 16 KiB [pipe][parity][tslot][lane]

    const int lw = wid < 3 ? wid : 2;
    const float* Wih = lw == 0 ? Wih0 : (lw == 1 ? Wih1 : Wih2);
    const float* Whh = lw == 0 ? Whh0 : (lw == 1 ? Whh1 : Whh2);
    const float* bih = lw == 0 ? bih0 : (lw == 1 ? bih1 : bih2);
    const float* bhh = lw == 0 ? bhh0 : (lw == 1 ? bhh1 : bhh2);

    // A-fragments of the log2e-SCALED weights (hi/lo split of scaled value):
    // aW[side][gate]; j-th bf16 = (j&1 ? Wlo : Whi)[n][4g+(j>>1)]
    short8 aW[2][3];
#pragma unroll
    for (int sd = 0; sd < 2; ++sd) {
        const float* W = sd ? Whh : Wih;
#pragma unroll
        for (int gate = 0; gate < 3; ++gate) {
            const float scale = gate == 2 ? KS2 : KS1;
            short8 f;
#pragma unroll
            for (int q = 0; q < 4; ++q) {
                const float w = scale * W[(gate * 16 + n) * 16 + (4 * g + q)];
                const ushort hi = bfbits(w);
                const ushort lo = bfbits(w - bf2f(hi));
                f[2 * q] = (short)hi; f[2 * q + 1] = (short)lo;
            }
            aW[sd][gate] = f;
        }
    }

    // Scaled biases in C layout (row m = 4g+j)
    f32x4 bR, bZ, bNX, bNH;
#pragma unroll
    for (int j = 0; j < 4; ++j) {
        const int m = 4 * g + j;
        bR[j]  = KS1 * (bih[m]      + bhh[m]);
        bZ[j]  = KS1 * (bih[16 + m] + bhh[16 + m]);
        bNX[j] = KS2 * bih[32 + m];
        bNH[j] = KS2 * bhh[32 + m];
    }

    // Embedding rows c = 4g+q (wave 0; e itself is UNSCALED — scale lives in A)
    float wex[4], wey[4], beq[4];
#pragma unroll
    for (int q = 0; q < 4; ++q) {
        const int c = 4 * g + q;
        wex[q] = W_emb[c * 2]; wey[q] = W_emb[c * 2 + 1]; beq[q] = b_emb[c];
    }
    // Output weights rows m = 4g+j (wave 3)
    float wo0[4], wo1[4];
#pragma unroll
    for (int j = 0; j < 4; ++j) { wo0[j] = W_out[4 * g + j]; wo1[j] = W_out[16 + 4 * g + j]; }
    const float bo0 = b_out[0], bo1 = b_out[1];

    f32x4 hC = *(const f32x4*)(h0 + ((size_t)lw * BB + b) * 16 + 4 * g);
    short8 hB = mk_b(hC);

    const float* xb = x + (size_t)b * (TT * 2);
    float4 xc0 = make_float4(0.f, 0.f, 0.f, 0.f), xc1 = xc0;
    if (wid == 0) { xc0 = *(const float4*)xb; xc1 = *(const float4*)(xb + 4); }

    // Gates with folded scaling: acc already equals -log2e*pre (r,z) / -2log2e*pre (n).
#define GATES(AR, AZ, ANH, ANX)                                         \
    do {                                                                \
        _Pragma("unroll")                                               \
        for (int j = 0; j < 4; ++j) {                                   \
            const float r = fast_rcp(1.0f + exp2f(AR[j]));              \
            const float z = fast_rcp(1.0f + exp2f(AZ[j]));              \
            const float En = exp2f(fmaf(r, ANH[j], ANX[j]));            \
            const float nn = fmaf(2.0f, fast_rcp(1.0f + En), -1.0f);    \
            hC[j] = fmaf(z, hC[j] - nn, nn);                            \
        }                                                               \
        hB = mk_b(hC);                                                  \
    } while (0)

#define HANDOFF(i)                                                      \
    do {                                                                \
        if (wid < 2) lbuf[p][s & 1][wid][i][l] = hB;                    \
        else         obuf[p][s & 1][i][l] = hC;                         \
    } while (0)

    const int NS = TT / 4 + 3;   // 131 supersteps
    for (int s = 0; s < NS; ++s) {
        const int t0 = 4 * (s - wid);
        if (t0 >= 0 && t0 < TT) {
            if (wid < 3) {
                short8 inB0, inB1, inB2, inB3;
                if (wid == 0) {
                    f32x4 e0, e1, e2, e3;
#pragma unroll
                    for (int q = 0; q < 4; ++q) {
                        e0[q] = fmaxf(fmaf(wey[q], xc0.y, fmaf(wex[q], xc0.x, beq[q])), 0.0f);
                        e1[q] = fmaxf(fmaf(wey[q], xc0.w, fmaf(wex[q], xc0.z, beq[q])), 0.0f);
                        e2[q] = fmaxf(fmaf(wey[q], xc1.y, fmaf(wex[q], xc1.x, beq[q])), 0.0f);
                        e3[q] = fmaxf(fmaf(wey[q], xc1.w, fmaf(wex[q], xc1.z, beq[q])), 0.0f);
                    }
                    inB0 = mk_b(e0); inB1 = mk_b(e1); inB2 = mk_b(e2); inB3 = mk_b(e3);
                    if (t0 + 4 < TT) {
                        xc0 = *(const float4*)(xb + (t0 + 4) * 2);
                        xc1 = *(const float4*)(xb + (t0 + 4) * 2 + 4);
                    }
                } else {
                    const int pp = (s - 1) & 1;
                    inB0 = lbuf[p][pp][wid - 1][0][l];
                    inB1 = lbuf[p][pp][wid - 1][1][l];
                    inB2 = lbuf[p][pp][wid - 1][2][l];
                    inB3 = lbuf[p][pp][wid - 1][3][l];
                }

                // ---- t0 ----
                f32x4 arA  = MFMA(aW[1][0], hB, bR);
                f32x4 azA  = MFMA(aW[1][1], hB, bZ);
                f32x4 anhA = MFMA(aW[1][2], hB, bNH);
                f32x4 anxA = MFMA(aW[0][2], inB0, bNX);
                arA = MFMA(aW[0][0], inB0, arA);
                azA = MFMA(aW[0][1], inB0, azA);
                f32x4 arB  = MFMA(aW[0][0], inB1, bR);     // pre-issue t1 x-side
                f32x4 azB  = MFMA(aW[0][1], inB1, bZ);
                f32x4 anxB = MFMA(aW[0][2], inB1, bNX);
                GATES(arA, azA, anhA, anxA);
                HANDOFF(0);
                // ---- t1 ----
                f32x4 anhB = MFMA(aW[1][2], hB, bNH);
                arB = MFMA(aW[1][0], hB, arB);
                azB = MFMA(aW[1][1], hB, azB);
                arA  = MFMA(aW[0][0], inB2, bR);           // pre-issue t2 x-side
                azA  = MFMA(aW[0][1], inB2, bZ);
                anxA = MFMA(aW[0][2], inB2, bNX);
                GATES(arB, azB, anhB, anxB);
                HANDOFF(1);
                // ---- t2 ----
                anhA = MFMA(aW[1][2], hB, bNH);
                arA = MFMA(aW[1][0], hB, arA);
                azA = MFMA(aW[1][1], hB, azA);
                arB  = MFMA(aW[0][0], inB3, bR);           // pre-issue t3 x-side
                azB  = MFMA(aW[0][1], inB3, bZ);
                anxB = MFMA(aW[0][2], inB3, bNX);
                GATES(arA, azA, anhA, anxA);
                HANDOFF(2);
                // ---- t3 ----
                anhB = MFMA(aW[1][2], hB, bNH);
                arB = MFMA(aW[1][0], hB, arB);
                azB = MFMA(aW[1][1], hB, azB);
                GATES(arB, azB, anhB, anxB);
                HANDOFF(3);
            } else {
                // ---- projection wave: t0..t0+3 (h2 from wave2, superstep s-1) ----
                const int pp = (s - 1) & 1;
                float pr[8];
#pragma unroll
                for (int i = 0; i < 4; ++i) {
                    const f32x4 h2 = obuf[p][pp][i][l];
                    float p0 = 0.f, p1 = 0.f;
#pragma unroll
                    for (int j = 0; j < 4; ++j) {
                        p0 = fmaf(wo0[j], h2[j], p0);
                        p1 = fmaf(wo1[j], h2[j], p1);
                    }
                    p0 += __shfl_xor(p0, 16); p0 += __shfl_xor(p0, 32);
                    p1 += __shfl_xor(p1, 16); p1 += __shfl_xor(p1, 32);
                    pr[2 * i] = p0 + bo0; pr[2 * i + 1] = p1 + bo1;
                }
                if (g == 0) {
                    float* op = out + (size_t)b * (TT * 2) + t0 * 2;
                    *(float4*)(op)     = make_float4(pr[0], pr[1], pr[2], pr[3]);
                    *(float4*)(op + 4) = make_float4(pr[4], pr[5], pr[6], pr[7]);
                }
            }
        }
        // LDS-only barrier (all 8 waves): drain ds ops, fence compiler, s_barrier.
        // vm loads/stores (x prefetch, out stores) deliberately stay in flight.
        asm volatile("s_waitcnt lgkmcnt(0)\n\ts_barrier" ::: "memory");
    }

    if (wid < 3)
        *(f32x4*)(out + (size_t)BB * TT * 2 + ((size_t)wid * BB + b) * 16 + 4 * g) = hC;

#undef GATES
#undef HANDOFF
}

extern "C" void kernel_launch(void* const* d_in, const int* in_sizes, int n_in,
                              void* d_out, int out_size, void* d_ws, size_t ws_size,
                              hipStream_t stream) {
    const float* x     = (const float*)d_in[0];
    const float* h0    = (const float*)d_in[1];
    const float* W_emb = (const float*)d_in[2];
    const float* b_emb = (const float*)d_in[3];
    const float* W_out = (const float*)d_in[4];
    const float* b_out = (const float*)d_in[5];
    const float* Wih0  = (const float*)d_in[6];
    const float* Whh0  = (const float*)d_in[7];
    const float* bih0  = (const float*)d_in[8];
    const float* bhh0  = (const float*)d_in[9];
    const float* Wih1  = (const float*)d_in[10];
    const float* Whh1  = (const float*)d_in[11];
    const float* bih1  = (const float*)d_in[12];
    const float* bhh1  = (const float*)d_in[13];
    const float* Wih2  = (const float*)d_in[14];
    const float* Whh2  = (const float*)d_in[15];
    const float* bih2  = (const float*)d_in[16];
    const float* bhh2  = (const float*)d_in[17];
    float* out = (float*)d_out;

    gru_pipe4x2_kernel<<<dim3(BB / 32), dim3(512), 0, stream>>>(
        x, h0, W_emb, b_emb, W_out, b_out,
        Wih0, Whh0, bih0, bhh0,
        Wih1, Whh1, bih1, bhh1,
        Wih2, Whh2, bih2, bhh2,
        out);
}

// Round 10
// 228.718 us; speedup vs baseline: 1.5744x; 1.5744x over previous
//
#include <hip/hip_runtime.h>
#include <hip/hip_bf16.h>

#define TT 512
#define BB 4096

typedef __attribute__((ext_vector_type(4))) float f32x4;
typedef __attribute__((ext_vector_type(8))) _Float16 f16x8;
typedef __attribute__((ext_vector_type(2))) _Float16 f16x2;
typedef __attribute__((ext_vector_type(2))) unsigned int uint2v;
typedef __attribute__((ext_vector_type(4))) unsigned int uint4v;

__device__ __forceinline__ f32x4 MFMA16(f16x8 a, f16x8 b, f32x4 c) {
    return __builtin_amdgcn_mfma_f32_16x16x32_f16(a, b, c, 0, 0, 0);
}

__device__ __forceinline__ float fast_rcp(float x) { return __builtin_amdgcn_rcpf(x); }

// Gate pre-activation scaling folded into weights/biases (validated R9):
//   r,z rows scaled by -log2(e) -> gate = rcp(1 + exp2(acc))
//   n rows scaled by -2*log2(e) -> tanh = 2*rcp(1 + exp2(acc)) - 1
#define KS1 (-1.44269504088896340736f)
#define KS2 (-2.88539008177792681472f)

// Layer-pipelined GRU, fused-K f16 MFMA, 4 timesteps/superstep, 4 waves:
//   waves 0..2 = layers (wave L does t=4(s-L)..+3 at superstep s), wave 3 = projection.
// K=32 packing, lane (n = lane&15, g = lane>>4), k = 8g+j:
//   j=0..3 -> input dims 4g+j (v: e or h_{L-1});  j=4..7 -> own-h dims 4g+(j-4).
// So B = { v-part: lane-aligned ds_read_b64 of upstream handoff,
//          h-part: own hC via 2x v_cvt_pkrtz } — no cross-lane traffic at all.
// r,z: one fused MFMA each; n: two MFMAs with zero-padded A halves (xn,hn separate).
__global__ __launch_bounds__(256, 1)
void gru_fk_kernel(const float* __restrict__ x, const float* __restrict__ h0,
                   const float* __restrict__ W_emb, const float* __restrict__ b_emb,
                   const float* __restrict__ W_out, const float* __restrict__ b_out,
                   const float* __restrict__ Wih0, const float* __restrict__ Whh0,
                   const float* __restrict__ bih0, const float* __restrict__ bhh0,
                   const float* __restrict__ Wih1, const float* __restrict__ Whh1,
                   const float* __restrict__ bih1, const float* __restrict__ bhh1,
                   const float* __restrict__ Wih2, const float* __restrict__ Whh2,
                   const float* __restrict__ bih2, const float* __restrict__ bhh2,
                   float* __restrict__ out)
{
    const int tid = threadIdx.x;
    const int wid = tid >> 6;      // 0..2 layer waves, 3 = projection wave
    const int l   = tid & 63;
    const int n   = l & 15;
    const int g   = l >> 4;
    const int b   = blockIdx.x * 16 + n;

    __shared__ uint2v lbuf[2][2][4][64];  // 8 KiB [parity][producer L][tslot][lane] f16x4
    __shared__ f32x4  obuf[2][4][64];     // 8 KiB [parity][tslot][lane] h2 in f32

    const int lw = wid < 3 ? wid : 2;
    const float* Wih = lw == 0 ? Wih0 : (lw == 1 ? Wih1 : Wih2);
    const float* Whh = lw == 0 ? Whh0 : (lw == 1 ? Whh1 : Whh2);
    const float* bih = lw == 0 ? bih0 : (lw == 1 ? bih1 : bih2);
    const float* bhh = lw == 0 ? bhh0 : (lw == 1 ? bhh1 : bhh2);

    // Fused A-fragments (f16, scale folded): row m = n, k = 8g+j.
    f16x8 aR, aZ, aNX, aNH;
#pragma unroll
    for (int q = 0; q < 4; ++q) {
        const int c = 4 * g + q;
        aR[q]     = (_Float16)(KS1 * Wih[(0 * 16 + n) * 16 + c]);
        aR[4 + q] = (_Float16)(KS1 * Whh[(0 * 16 + n) * 16 + c]);
        aZ[q]     = (_Float16)(KS1 * Wih[(1 * 16 + n) * 16 + c]);
        aZ[4 + q] = (_Float16)(KS1 * Whh[(1 * 16 + n) * 16 + c]);
        aNX[q]    = (_Float16)(KS2 * Wih[(2 * 16 + n) * 16 + c]);
        aNX[4 + q] = (_Float16)0.0f;
        aNH[q]     = (_Float16)0.0f;
        aNH[4 + q] = (_Float16)(KS2 * Whh[(2 * 16 + n) * 16 + c]);
    }

    // Scaled biases in C layout (row m = 4g+j)
    f32x4 bR, bZ, bNX, bNH;
#pragma unroll
    for (int j = 0; j < 4; ++j) {
        const int m = 4 * g + j;
        bR[j]  = KS1 * (bih[m]      + bhh[m]);
        bZ[j]  = KS1 * (bih[16 + m] + bhh[16 + m]);
        bNX[j] = KS2 * bih[32 + m];
        bNH[j] = KS2 * bhh[32 + m];
    }

    // Embedding rows c = 4g+q (wave 0; e UNSCALED — scale lives in A)
    float wex[4], wey[4], beq[4];
#pragma unroll
    for (int q = 0; q < 4; ++q) {
        const int c = 4 * g + q;
        wex[q] = W_emb[c * 2]; wey[q] = W_emb[c * 2 + 1]; beq[q] = b_emb[c];
    }
    // Output weights rows m = 4g+j (wave 3)
    float wo0[4], wo1[4];
#pragma unroll
    for (int j = 0; j < 4; ++j) { wo0[j] = W_out[4 * g + j]; wo1[j] = W_out[16 + 4 * g + j]; }
    const float bo0 = b_out[0], bo1 = b_out[1];

    // Hidden state: f32 rows 4g+j (C layout) + packed f16 pair for the B h-part
    f32x4 hC = *(const f32x4*)(h0 + ((size_t)lw * BB + b) * 16 + 4 * g);
    uint2v hPK;
    hPK.x = __builtin_bit_cast(unsigned int, __builtin_amdgcn_cvt_pkrtz(hC[0], hC[1]));
    hPK.y = __builtin_bit_cast(unsigned int, __builtin_amdgcn_cvt_pkrtz(hC[2], hC[3]));

    const float* xb = x + (size_t)b * (TT * 2);
    float4 xc0 = make_float4(0.f, 0.f, 0.f, 0.f), xc1 = xc0;
    if (wid == 0) { xc0 = *(const float4*)xb; xc1 = *(const float4*)(xb + 4); }

#define STEP(inV, slot)                                                       \
    do {                                                                      \
        uint4v bw;                                                            \
        bw.x = (inV).x; bw.y = (inV).y; bw.z = hPK.x; bw.w = hPK.y;           \
        const f16x8 Bf = __builtin_bit_cast(f16x8, bw);                       \
        f32x4 ar  = MFMA16(aR,  Bf, bR);                                      \
        f32x4 az  = MFMA16(aZ,  Bf, bZ);                                      \
        f32x4 anx = MFMA16(aNX, Bf, bNX);                                     \
        f32x4 anh = MFMA16(aNH, Bf, bNH);                                     \
        _Pragma("unroll")                                                     \
        for (int j = 0; j < 4; ++j) {                                         \
            const float r = fast_rcp(1.0f + exp2f(ar[j]));                    \
            const float z = fast_rcp(1.0f + exp2f(az[j]));                    \
            const float En = exp2f(fmaf(r, anh[j], anx[j]));                  \
            const float nn = fmaf(2.0f, fast_rcp(1.0f + En), -1.0f);          \
            hC[j] = fmaf(z, hC[j] - nn, nn);                                  \
        }                                                                     \
        hPK.x = __builtin_bit_cast(unsigned int,                              \
                    __builtin_amdgcn_cvt_pkrtz(hC[0], hC[1]));                \
        hPK.y = __builtin_bit_cast(unsigned int,                              \
                    __builtin_amdgcn_cvt_pkrtz(hC[2], hC[3]));                \
        if (wid < 2) lbuf[s & 1][wid][slot][l] = hPK;                         \
        else         obuf[s & 1][slot][l] = hC;                               \
    } while (0)

    const int NS = TT / 4 + 3;   // 131 supersteps
    for (int s = 0; s < NS; ++s) {
        const int t0 = 4 * (s - wid);
        if (t0 >= 0 && t0 < TT) {
            if (wid < 3) {
                // v-part fragments for t0..t0+3 (lane-aligned)
                uint2v inV0, inV1, inV2, inV3;
                if (wid == 0) {
                    f32x4 e0, e1, e2, e3;
#pragma unroll
                    for (int q = 0; q < 4; ++q) {
                        e0[q] = fmaxf(fmaf(wey[q], xc0.y, fmaf(wex[q], xc0.x, beq[q])), 0.0f);
                        e1[q] = fmaxf(fmaf(wey[q], xc0.w, fmaf(wex[q], xc0.z, beq[q])), 0.0f);
                        e2[q] = fmaxf(fmaf(wey[q], xc1.y, fmaf(wex[q], xc1.x, beq[q])), 0.0f);
                        e3[q] = fmaxf(fmaf(wey[q], xc1.w, fmaf(wex[q], xc1.z, beq[q])), 0.0f);
                    }
                    inV0.x = __builtin_bit_cast(unsigned int, __builtin_amdgcn_cvt_pkrtz(e0[0], e0[1]));
                    inV0.y = __builtin_bit_cast(unsigned int, __builtin_amdgcn_cvt_pkrtz(e0[2], e0[3]));
                    inV1.x = __builtin_bit_cast(unsigned int, __builtin_amdgcn_cvt_pkrtz(e1[0], e1[1]));
                    inV1.y = __builtin_bit_cast(unsigned int, __builtin_amdgcn_cvt_pkrtz(e1[2], e1[3]));
                    inV2.x = __builtin_bit_cast(unsigned int, __builtin_amdgcn_cvt_pkrtz(e2[0], e2[1]));
                    inV2.y = __builtin_bit_cast(unsigned int, __builtin_amdgcn_cvt_pkrtz(e2[2], e2[3]));
                    inV3.x = __builtin_bit_cast(unsigned int, __builtin_amdgcn_cvt_pkrtz(e3[0], e3[1]));
                    inV3.y = __builtin_bit_cast(unsigned int, __builtin_amdgcn_cvt_pkrtz(e3[2], e3[3]));
                    if (t0 + 4 < TT) {
                        xc0 = *(const float4*)(xb + (t0 + 4) * 2);
                        xc1 = *(const float4*)(xb + (t0 + 4) * 2 + 4);
                    }
                } else {
                    const int pp = (s - 1) & 1;
                    inV0 = lbuf[pp][wid - 1][0][l];
                    inV1 = lbuf[pp][wid - 1][1][l];
                    inV2 = lbuf[pp][wid - 1][2][l];
                    inV3 = lbuf[pp][wid - 1][3][l];
                }
                STEP(inV0, 0);
                STEP(inV1, 1);
                STEP(inV2, 2);
                STEP(inV3, 3);
            } else {
                // projection wave: t0..t0+3 (h2 from wave2, superstep s-1)
                const int pp = (s - 1) & 1;
                float pr[8];
#pragma unroll
                for (int i = 0; i < 4; ++i) {
                    const f32x4 h2 = obuf[pp][i][l];
                    float p0 = 0.f, p1 = 0.f;
#pragma unroll
                    for (int j = 0; j < 4; ++j) {
                        p0 = fmaf(wo0[j], h2[j], p0);
                        p1 = fmaf(wo1[j], h2[j], p1);
                    }
                    p0 += __shfl_xor(p0, 16); p0 += __shfl_xor(p0, 32);
                    p1 += __shfl_xor(p1, 16); p1 += __shfl_xor(p1, 32);
                    pr[2 * i] = p0 + bo0; pr[2 * i + 1] = p1 + bo1;
                }
                if (g == 0) {
                    float* op = out + (size_t)b * (TT * 2) + t0 * 2;
                    *(float4*)(op)     = make_float4(pr[0], pr[1], pr[2], pr[3]);
                    *(float4*)(op + 4) = make_float4(pr[4], pr[5], pr[6], pr[7]);
                }
            }
        }
        // LDS-only barrier: drain ds ops, fence compiler, s_barrier.
        // vm loads/stores (x prefetch, out stores) deliberately stay in flight.
        asm volatile("s_waitcnt lgkmcnt(0)\n\ts_barrier" ::: "memory");
    }

    // Final hidden state: layer waves store their own layer (f32 C rows).
    if (wid < 3)
        *(f32x4*)(out + (size_t)BB * TT * 2 + ((size_t)wid * BB + b) * 16 + 4 * g) = hC;

#undef STEP
}

extern "C" void kernel_launch(void* const* d_in, const int* in_sizes, int n_in,
                              void* d_out, int out_size, void* d_ws, size_t ws_size,
                              hipStream_t stream) {
    const float* x     = (const float*)d_in[0];
    const float* h0    = (const float*)d_in[1];
    const float* W_emb = (const float*)d_in[2];
    const float* b_emb = (const float*)d_in[3];
    const float* W_out = (const float*)d_in[4];
    const float* b_out = (const float*)d_in[5];
    const float* Wih0  = (const float*)d_in[6];
    const float* Whh0  = (const float*)d_in[7];
    const float* bih0  = (const float*)d_in[8];
    const float* bhh0  = (const float*)d_in[9];
    const float* Wih1  = (const float*)d_in[10];
    const float* Whh1  = (const float*)d_in[11];
    const float* bih1  = (const float*)d_in[12];
    const float* bhh1  = (const float*)d_in[13];
    const float* Wih2  = (const float*)d_in[14];
    const float* Whh2  = (const float*)d_in[15];
    const float* bih2  = (const float*)d_in[16];
    const float* bhh2  = (const float*)d_in[17];
    float* out = (float*)d_out;

    gru_fk_kernel<<<dim3(BB / 16), dim3(256), 0, stream>>>(
        x, h0, W_emb, b_emb, W_out, b_out,
        Wih0, Whh0, bih0, bhh0,
        Wih1, Whh1, bih1, bhh1,
        Wih2, Whh2, bih2, bhh2,
        out);
}